// Round 2
// baseline (329.600 us; speedup 1.0000x reference)
//
#include <hip/hip_runtime.h>
#include <stdint.h>

#define D 256

typedef __bf16 bf16x8 __attribute__((ext_vector_type(8)));
typedef unsigned short u16x8 __attribute__((ext_vector_type(8)));
typedef float f32x4 __attribute__((ext_vector_type(4)));

static __device__ inline unsigned short f2bf(float f) {
    union { float f; unsigned u; } c; c.f = f;
    unsigned u = c.u + 0x7FFFu + ((c.u >> 16) & 1u);   // RNE round to bf16
    return (unsigned short)(u >> 16);
}

// ---- K1: histogram of dst ----
__global__ void count_kernel(const int* __restrict__ dst, int* __restrict__ cnt, int E) {
    int e = blockIdx.x * blockDim.x + threadIdx.x;
    if (e < E) atomicAdd(&cnt[dst[e]], 1);
}

// ---- K2: single-block chunked exclusive scan -> offs[0..n], cur[0..n-1] ----
__global__ __launch_bounds__(1024) void scan_kernel(const int* __restrict__ cnt,
        int* __restrict__ offs, int* __restrict__ cur, int n, int CH) {
    int t = threadIdx.x;
    int base_idx = t * CH;
    int s = 0;
    for (int i = 0; i < CH; ++i) {
        int idx = base_idx + i;
        if (idx < n) s += cnt[idx];
    }
    __shared__ int tmp[1024];
    tmp[t] = s;
    __syncthreads();
    for (int off = 1; off < 1024; off <<= 1) {
        int v = 0;
        if (t >= off) v = tmp[t - off];
        __syncthreads();
        tmp[t] += v;
        __syncthreads();
    }
    int incl = tmp[t];
    int total = tmp[1023];
    int running = incl - s;
    for (int i = 0; i < CH; ++i) {
        int idx = base_idx + i;
        if (idx < n) {
            offs[idx] = running;
            cur[idx]  = running;
            running += cnt[idx];
        }
    }
    if (t == 0) offs[n] = total;
}

// ---- K3: bucket-fill (src, w) sorted by dst ----
__global__ void fill_kernel(const int* __restrict__ dst, const int* __restrict__ src,
        const float* __restrict__ ew, int* __restrict__ cur,
        int* __restrict__ srcS, float* __restrict__ wS, int E) {
    int e = blockIdx.x * blockDim.x + threadIdx.x;
    if (e < E) {
        int d = dst[e];
        int pos = atomicAdd(&cur[d], 1);
        srcS[pos] = src[e];
        wS[pos]   = ew[e];
    }
}

// ---- K4: aggregate out[n,:] = sum_e w_e * X[src_e,:]  (one wave per node) ----
// Writes the aggregate INTO d_out; the GEMM then runs row-in-place.
__global__ __launch_bounds__(256) void agg_kernel(const float4* __restrict__ X4,
        const int* __restrict__ offs, const int* __restrict__ srcS,
        const float* __restrict__ wS, float4* __restrict__ agg4, int N) {
    int wave = threadIdx.x >> 6;
    int lane = threadIdx.x & 63;
    int node = blockIdx.x * 4 + wave;
    if (node >= N) return;
    int beg = offs[node], end = offs[node + 1];
    float ax = 0.f, ay = 0.f, az = 0.f, aw = 0.f;
    for (int e = beg; e < end; ++e) {
        int sN = srcS[e];
        float wt = wS[e];
        float4 xv = X4[(size_t)sN * 64 + lane];
        ax += wt * xv.x; ay += wt * xv.y; az += wt * xv.z; aw += wt * xv.w;
    }
    float4 r; r.x = ax; r.y = ay; r.z = az; r.w = aw;
    agg4[(size_t)node * 64 + lane] = r;
}

// ---- K5: out = A @ W^T via bf16 MFMA, IN-PLACE (A == out). BM=64, BN=256, BK=32.
// Safe: block b reads only rows [m0, m0+64) across the whole k-loop, then
// writes exactly those rows in the epilogue. No cross-block row aliasing.
__global__ __launch_bounds__(256) void gemm_kernel(const float* __restrict__ A,
        const float* __restrict__ Wp, float* __restrict__ out, int M) {
    __shared__ u16x8 Asm[4 * 64];    // [kc][row]  4KB
    __shared__ u16x8 Bsm[4 * 256];   // [kc][n]   16KB

    int tid  = threadIdx.x;
    int lane = tid & 63;
    int wn   = tid >> 6;          // wave id = N-quadrant
    int m0   = blockIdx.x * 64;

    f32x4 acc[4][4];
#pragma unroll
    for (int i = 0; i < 4; ++i)
#pragma unroll
        for (int j = 0; j < 4; ++j)
            acc[i][j] = (f32x4){0.f, 0.f, 0.f, 0.f};

    int arow = tid >> 2;          // 0..63
    int akc  = tid & 3;           // 0..3
    int grow = m0 + arow; if (grow > M - 1) grow = M - 1;
    const float* aBase = A + (size_t)grow * D + akc * 8;

    int l16 = lane & 15, lq = lane >> 4;

    for (int s = 0; s < 8; ++s) {
        int k0 = s * 32;
        // stage A tile (64 x 32 f32 -> bf16)
        {
            const float4* p = (const float4*)(aBase + k0);
            float4 v0 = p[0], v1 = p[1];
            u16x8 h;
            h[0] = f2bf(v0.x); h[1] = f2bf(v0.y); h[2] = f2bf(v0.z); h[3] = f2bf(v0.w);
            h[4] = f2bf(v1.x); h[5] = f2bf(v1.y); h[6] = f2bf(v1.z); h[7] = f2bf(v1.w);
            Asm[akc * 64 + arow] = h;
        }
        // stage B tile (256 x 32 f32 -> bf16), B = W rows (C = A * W^T)
#pragma unroll
        for (int j = 0; j < 4; ++j) {
            int n = j * 64 + (tid >> 2);
            const float4* p = (const float4*)(Wp + (size_t)n * D + k0 + akc * 8);
            float4 v0 = p[0], v1 = p[1];
            u16x8 h;
            h[0] = f2bf(v0.x); h[1] = f2bf(v0.y); h[2] = f2bf(v0.z); h[3] = f2bf(v0.w);
            h[4] = f2bf(v1.x); h[5] = f2bf(v1.y); h[6] = f2bf(v1.z); h[7] = f2bf(v1.w);
            Bsm[akc * 256 + n] = h;
        }
        __syncthreads();

        u16x8 af[4], bfr[4];
#pragma unroll
        for (int fm = 0; fm < 4; ++fm) af[fm] = Asm[lq * 64 + fm * 16 + l16];
#pragma unroll
        for (int fn = 0; fn < 4; ++fn) bfr[fn] = Bsm[lq * 256 + wn * 64 + fn * 16 + l16];
#pragma unroll
        for (int fm = 0; fm < 4; ++fm)
#pragma unroll
            for (int fn = 0; fn < 4; ++fn)
                acc[fm][fn] = __builtin_amdgcn_mfma_f32_16x16x32_bf16(
                    __builtin_bit_cast(bf16x8, af[fm]),
                    __builtin_bit_cast(bf16x8, bfr[fn]),
                    acc[fm][fn], 0, 0, 0);
        __syncthreads();
    }

    // epilogue: C/D map row=(lane>>4)*4+reg, col=lane&15
#pragma unroll
    for (int fm = 0; fm < 4; ++fm)
#pragma unroll
        for (int fn = 0; fn < 4; ++fn)
#pragma unroll
            for (int r = 0; r < 4; ++r) {
                int row = m0 + fm * 16 + lq * 4 + r;
                int col = wn * 64 + fn * 16 + l16;
                if (row < M) out[(size_t)row * D + col] = acc[fm][fn][r];
            }
}

extern "C" void kernel_launch(void* const* d_in, const int* in_sizes, int n_in,
                              void* d_out, int out_size, void* d_ws, size_t ws_size,
                              hipStream_t stream) {
    const float* X  = (const float*)d_in[0];
    const int*   ei = (const int*)d_in[1];
    const float* ew = (const float*)d_in[2];
    const float* Wp = (const float*)d_in[3];
    float* out = (float*)d_out;

    int N = in_sizes[0] / D;       // 50000
    int E = in_sizes[2];           // 300000
    const int* dst = ei;
    const int* src = ei + E;

    // workspace: only CSR metadata + sorted edge arrays (~3.0 MB total)
    int* cnt  = (int*)d_ws;                            // N
    int* offs = cnt + N;                               // N+1
    int* cur  = offs + N + 1;                          // N
    int* srcS = cur + N;                               // E
    float* wS = (float*)(srcS + E);                    // E

    hipMemsetAsync(cnt, 0, (size_t)N * sizeof(int), stream);
    count_kernel<<<dim3((E + 255) / 256), dim3(256), 0, stream>>>(dst, cnt, E);
    int CH = (N + 1023) / 1024;
    scan_kernel<<<dim3(1), dim3(1024), 0, stream>>>(cnt, offs, cur, N, CH);
    fill_kernel<<<dim3((E + 255) / 256), dim3(256), 0, stream>>>(dst, src, ew, cur, srcS, wS, E);
    // aggregate directly into d_out (scratch at this point)
    agg_kernel<<<dim3((N + 3) / 4), dim3(256), 0, stream>>>((const float4*)X, offs, srcS, wS,
                                                            (float4*)out, N);
    // in-place row-local GEMM: out = out @ W^T
    gemm_kernel<<<dim3((N + 63) / 64), dim3(256), 0, stream>>>(out, Wp, out, N);
}

// Round 3
// 215.565 us; speedup vs baseline: 1.5290x; 1.5290x over previous
//
#include <hip/hip_runtime.h>
#include <stdint.h>

#define D 256

typedef __bf16 bf16x8 __attribute__((ext_vector_type(8)));
typedef unsigned short u16x8 __attribute__((ext_vector_type(8)));
typedef float f32x4 __attribute__((ext_vector_type(4)));

static __device__ inline unsigned short f2bf(float f) {
    union { float f; unsigned u; } c; c.f = f;
    unsigned u = c.u + 0x7FFFu + ((c.u >> 16) & 1u);   // RNE round to bf16
    return (unsigned short)(u >> 16);
}

// ---- K1: histogram of dst ----
__global__ void count_kernel(const int* __restrict__ dst, int* __restrict__ cnt, int E) {
    int e = blockIdx.x * blockDim.x + threadIdx.x;
    if (e < E) atomicAdd(&cnt[dst[e]], 1);
}

// ---- K2a: per-1024-block exclusive scan + block sums ----
__global__ __launch_bounds__(1024) void scan_local_kernel(const int* __restrict__ cnt,
        int* __restrict__ exsc, int* __restrict__ bsum, int n) {
    int t = threadIdx.x;
    int idx = blockIdx.x * 1024 + t;
    int v = (idx < n) ? cnt[idx] : 0;
    __shared__ int tmp[1024];
    tmp[t] = v;
    __syncthreads();
    for (int off = 1; off < 1024; off <<= 1) {
        int u = 0;
        if (t >= off) u = tmp[t - off];
        __syncthreads();
        tmp[t] += u;
        __syncthreads();
    }
    if (idx < n) exsc[idx] = tmp[t] - v;          // exclusive within block
    if (t == 1023) bsum[blockIdx.x] = tmp[t];     // block total
}

// ---- K2b: exclusive scan of block sums (single small block, nb <= 1024) ----
__global__ __launch_bounds__(1024) void scan_bsum_kernel(int* __restrict__ bsum, int nb) {
    int t = threadIdx.x;
    int v = (t < nb) ? bsum[t] : 0;
    __shared__ int tmp[1024];
    tmp[t] = v;
    __syncthreads();
    for (int off = 1; off < 1024; off <<= 1) {
        int u = 0;
        if (t >= off) u = tmp[t - off];
        __syncthreads();
        tmp[t] += u;
        __syncthreads();
    }
    if (t < nb) bsum[t] = tmp[t] - v;             // exclusive
}

// ---- K2c: offs[i] = exsc[i] + bsum[i/1024]; cur = offs; offs[n] = E ----
__global__ void scan_finalize_kernel(const int* __restrict__ exsc, const int* __restrict__ bsum,
        int* __restrict__ offs, int* __restrict__ cur, int n, int E) {
    int idx = blockIdx.x * blockDim.x + threadIdx.x;
    if (idx < n) {
        int o = exsc[idx] + bsum[idx >> 10];
        offs[idx] = o;
        cur[idx]  = o;
    }
    if (idx == 0) offs[n] = E;
}

// ---- K3: bucket-fill (src, w) sorted by dst ----
__global__ void fill_kernel(const int* __restrict__ dst, const int* __restrict__ src,
        const float* __restrict__ ew, int* __restrict__ cur,
        int* __restrict__ srcS, float* __restrict__ wS, int E) {
    int e = blockIdx.x * blockDim.x + threadIdx.x;
    if (e < E) {
        int d = dst[e];
        int pos = atomicAdd(&cur[d], 1);
        srcS[pos] = src[e];
        wS[pos]   = ew[e];
    }
}

// ---- K4: aggregate out[n,:] = sum_e w_e * X[src_e,:]  (one wave per node) ----
// Writes the aggregate INTO d_out; the GEMM then runs row-in-place.
__global__ __launch_bounds__(256) void agg_kernel(const float4* __restrict__ X4,
        const int* __restrict__ offs, const int* __restrict__ srcS,
        const float* __restrict__ wS, float4* __restrict__ agg4, int N) {
    int wave = threadIdx.x >> 6;
    int lane = threadIdx.x & 63;
    int node = blockIdx.x * 4 + wave;
    if (node >= N) return;
    int beg = offs[node], end = offs[node + 1];
    float ax = 0.f, ay = 0.f, az = 0.f, aw = 0.f;
    for (int e = beg; e < end; ++e) {
        int sN = srcS[e];
        float wt = wS[e];
        float4 xv = X4[(size_t)sN * 64 + lane];
        ax += wt * xv.x; ay += wt * xv.y; az += wt * xv.z; aw += wt * xv.w;
    }
    float4 r; r.x = ax; r.y = ay; r.z = az; r.w = aw;
    agg4[(size_t)node * 64 + lane] = r;
}

// ---- K5: out = A @ W^T via bf16 MFMA, IN-PLACE (A == out). BM=64, BN=256, BK=32.
__global__ __launch_bounds__(256) void gemm_kernel(const float* __restrict__ A,
        const float* __restrict__ Wp, float* __restrict__ out, int M) {
    __shared__ u16x8 Asm[4 * 64];    // [kc][row]  4KB
    __shared__ u16x8 Bsm[4 * 256];   // [kc][n]   16KB

    int tid  = threadIdx.x;
    int lane = tid & 63;
    int wn   = tid >> 6;          // wave id = N-quadrant
    int m0   = blockIdx.x * 64;

    f32x4 acc[4][4];
#pragma unroll
    for (int i = 0; i < 4; ++i)
#pragma unroll
        for (int j = 0; j < 4; ++j)
            acc[i][j] = (f32x4){0.f, 0.f, 0.f, 0.f};

    int arow = tid >> 2;          // 0..63
    int akc  = tid & 3;           // 0..3
    int grow = m0 + arow; if (grow > M - 1) grow = M - 1;
    const float* aBase = A + (size_t)grow * D + akc * 8;

    int l16 = lane & 15, lq = lane >> 4;

    for (int s = 0; s < 8; ++s) {
        int k0 = s * 32;
        // stage A tile (64 x 32 f32 -> bf16)
        {
            const float4* p = (const float4*)(aBase + k0);
            float4 v0 = p[0], v1 = p[1];
            u16x8 h;
            h[0] = f2bf(v0.x); h[1] = f2bf(v0.y); h[2] = f2bf(v0.z); h[3] = f2bf(v0.w);
            h[4] = f2bf(v1.x); h[5] = f2bf(v1.y); h[6] = f2bf(v1.z); h[7] = f2bf(v1.w);
            Asm[akc * 64 + arow] = h;
        }
        // stage B tile (256 x 32 f32 -> bf16), B = W rows (C = A * W^T)
#pragma unroll
        for (int j = 0; j < 4; ++j) {
            int n = j * 64 + (tid >> 2);
            const float4* p = (const float4*)(Wp + (size_t)n * D + k0 + akc * 8);
            float4 v0 = p[0], v1 = p[1];
            u16x8 h;
            h[0] = f2bf(v0.x); h[1] = f2bf(v0.y); h[2] = f2bf(v0.z); h[3] = f2bf(v0.w);
            h[4] = f2bf(v1.x); h[5] = f2bf(v1.y); h[6] = f2bf(v1.z); h[7] = f2bf(v1.w);
            Bsm[akc * 256 + n] = h;
        }
        __syncthreads();

        u16x8 af[4], bfr[4];
#pragma unroll
        for (int fm = 0; fm < 4; ++fm) af[fm] = Asm[lq * 64 + fm * 16 + l16];
#pragma unroll
        for (int fn = 0; fn < 4; ++fn) bfr[fn] = Bsm[lq * 256 + wn * 64 + fn * 16 + l16];
#pragma unroll
        for (int fm = 0; fm < 4; ++fm)
#pragma unroll
            for (int fn = 0; fn < 4; ++fn)
                acc[fm][fn] = __builtin_amdgcn_mfma_f32_16x16x32_bf16(
                    __builtin_bit_cast(bf16x8, af[fm]),
                    __builtin_bit_cast(bf16x8, bfr[fn]),
                    acc[fm][fn], 0, 0, 0);
        __syncthreads();
    }

    // epilogue: C/D map row=(lane>>4)*4+reg, col=lane&15
#pragma unroll
    for (int fm = 0; fm < 4; ++fm)
#pragma unroll
        for (int fn = 0; fn < 4; ++fn)
#pragma unroll
            for (int r = 0; r < 4; ++r) {
                int row = m0 + fm * 16 + lq * 4 + r;
                int col = wn * 64 + fn * 16 + l16;
                if (row < M) out[(size_t)row * D + col] = acc[fm][fn][r];
            }
}

extern "C" void kernel_launch(void* const* d_in, const int* in_sizes, int n_in,
                              void* d_out, int out_size, void* d_ws, size_t ws_size,
                              hipStream_t stream) {
    const float* X  = (const float*)d_in[0];
    const int*   ei = (const int*)d_in[1];
    const float* ew = (const float*)d_in[2];
    const float* Wp = (const float*)d_in[3];
    float* out = (float*)d_out;

    int N = in_sizes[0] / D;       // 50000
    int E = in_sizes[2];           // 300000
    const int* dst = ei;
    const int* src = ei + E;

    int nb = (N + 1023) / 1024;    // 49 scan blocks

    // workspace (~3.2 MB)
    int* cnt  = (int*)d_ws;                            // N
    int* offs = cnt + N;                               // N+1
    int* cur  = offs + N + 1;                          // N
    int* srcS = cur + N;                               // E
    float* wS = (float*)(srcS + E);                    // E
    int* exsc = (int*)(wS + E);                        // N
    int* bsum = exsc + N;                              // nb

    hipMemsetAsync(cnt, 0, (size_t)N * sizeof(int), stream);
    count_kernel<<<dim3((E + 255) / 256), dim3(256), 0, stream>>>(dst, cnt, E);
    scan_local_kernel<<<dim3(nb), dim3(1024), 0, stream>>>(cnt, exsc, bsum, N);
    scan_bsum_kernel<<<dim3(1), dim3(1024), 0, stream>>>(bsum, nb);
    scan_finalize_kernel<<<dim3((N + 255) / 256), dim3(256), 0, stream>>>(exsc, bsum, offs, cur, N, E);
    fill_kernel<<<dim3((E + 255) / 256), dim3(256), 0, stream>>>(dst, src, ew, cur, srcS, wS, E);
    // aggregate directly into d_out (scratch at this point)
    agg_kernel<<<dim3((N + 3) / 4), dim3(256), 0, stream>>>((const float4*)X, offs, srcS, wS,
                                                            (float4*)out, N);
    // in-place row-local GEMM: out = out @ W^T
    gemm_kernel<<<dim3((N + 63) / 64), dim3(256), 0, stream>>>(out, Wp, out, N);
}

// Round 4
// 210.067 us; speedup vs baseline: 1.5690x; 1.0262x over previous
//
#include <hip/hip_runtime.h>
#include <stdint.h>

#define D 256

typedef __bf16 bf16x8 __attribute__((ext_vector_type(8)));
typedef unsigned short u16x8 __attribute__((ext_vector_type(8)));
typedef float f32x4 __attribute__((ext_vector_type(4)));

static __device__ inline unsigned short f2bf(float f) {
    union { float f; unsigned u; } c; c.f = f;
    unsigned u = c.u + 0x7FFFu + ((c.u >> 16) & 1u);   // RNE round to bf16
    return (unsigned short)(u >> 16);
}
static __device__ inline float bf2f(unsigned short h) {
    union { unsigned u; float f; } c; c.u = (unsigned)h << 16;
    return c.f;
}

// ---- K0: X (f32) -> Xb (bf16), 8 elems/thread ----
__global__ void convert_kernel(const float4* __restrict__ X4, u16x8* __restrict__ Xb, size_t n8) {
    size_t i = (size_t)blockIdx.x * blockDim.x + threadIdx.x;
    if (i < n8) {
        float4 a = X4[2 * i], b = X4[2 * i + 1];
        u16x8 h;
        h[0] = f2bf(a.x); h[1] = f2bf(a.y); h[2] = f2bf(a.z); h[3] = f2bf(a.w);
        h[4] = f2bf(b.x); h[5] = f2bf(b.y); h[6] = f2bf(b.z); h[7] = f2bf(b.w);
        Xb[i] = h;
    }
}

// ---- K1: histogram of dst ----
__global__ void count_kernel(const int* __restrict__ dst, int* __restrict__ cnt, int E) {
    int e = blockIdx.x * blockDim.x + threadIdx.x;
    if (e < E) atomicAdd(&cnt[dst[e]], 1);
}

// ---- K2a: per-1024-block exclusive scan + block sums ----
__global__ __launch_bounds__(1024) void scan_local_kernel(const int* __restrict__ cnt,
        int* __restrict__ exsc, int* __restrict__ bsum, int n) {
    int t = threadIdx.x;
    int idx = blockIdx.x * 1024 + t;
    int v = (idx < n) ? cnt[idx] : 0;
    __shared__ int tmp[1024];
    tmp[t] = v;
    __syncthreads();
    for (int off = 1; off < 1024; off <<= 1) {
        int u = 0;
        if (t >= off) u = tmp[t - off];
        __syncthreads();
        tmp[t] += u;
        __syncthreads();
    }
    if (idx < n) exsc[idx] = tmp[t] - v;
    if (t == 1023) bsum[blockIdx.x] = tmp[t];
}

// ---- K2b: exclusive scan of block sums (nb <= 1024) ----
__global__ __launch_bounds__(1024) void scan_bsum_kernel(int* __restrict__ bsum, int nb) {
    int t = threadIdx.x;
    int v = (t < nb) ? bsum[t] : 0;
    __shared__ int tmp[1024];
    tmp[t] = v;
    __syncthreads();
    for (int off = 1; off < 1024; off <<= 1) {
        int u = 0;
        if (t >= off) u = tmp[t - off];
        __syncthreads();
        tmp[t] += u;
        __syncthreads();
    }
    if (t < nb) bsum[t] = tmp[t] - v;
}

// ---- K2c: offs[i] = exsc[i] + bsum[i/1024]; cur = offs; offs[n] = E ----
__global__ void scan_finalize_kernel(const int* __restrict__ exsc, const int* __restrict__ bsum,
        int* __restrict__ offs, int* __restrict__ cur, int n, int E) {
    int idx = blockIdx.x * blockDim.x + threadIdx.x;
    if (idx < n) {
        int o = exsc[idx] + bsum[idx >> 10];
        offs[idx] = o;
        cur[idx]  = o;
    }
    if (idx == 0) offs[n] = E;
}

// ---- K3: bucket-fill (src, w) sorted by dst ----
__global__ void fill_kernel(const int* __restrict__ dst, const int* __restrict__ src,
        const float* __restrict__ ew, int* __restrict__ cur,
        int* __restrict__ srcS, float* __restrict__ wS, int E) {
    int e = blockIdx.x * blockDim.x + threadIdx.x;
    if (e < E) {
        int d = dst[e];
        int pos = atomicAdd(&cur[d], 1);
        srcS[pos] = src[e];
        wS[pos]   = ew[e];
    }
}

// ---- K4b: aggregate from bf16 X rows (512B gather), f32 accum, one wave/node ----
__global__ __launch_bounds__(256) void aggb_kernel(const ushort4* __restrict__ Xb,
        const int* __restrict__ offs, const int* __restrict__ srcS,
        const float* __restrict__ wS, float4* __restrict__ out4, int N) {
    int wave = threadIdx.x >> 6;
    int lane = threadIdx.x & 63;
    int node = blockIdx.x * 4 + wave;
    if (node >= N) return;
    int beg = offs[node], end = offs[node + 1];
    float ax = 0.f, ay = 0.f, az = 0.f, aw = 0.f;
    int e = beg;
    for (; e + 1 < end; e += 2) {
        int s0 = srcS[e],     s1 = srcS[e + 1];
        float w0 = wS[e],     w1 = wS[e + 1];
        ushort4 h0 = Xb[(size_t)s0 * 64 + lane];
        ushort4 h1 = Xb[(size_t)s1 * 64 + lane];
        ax += w0 * bf2f(h0.x); ay += w0 * bf2f(h0.y);
        az += w0 * bf2f(h0.z); aw += w0 * bf2f(h0.w);
        ax += w1 * bf2f(h1.x); ay += w1 * bf2f(h1.y);
        az += w1 * bf2f(h1.z); aw += w1 * bf2f(h1.w);
    }
    if (e < end) {
        int s0 = srcS[e];
        float w0 = wS[e];
        ushort4 h0 = Xb[(size_t)s0 * 64 + lane];
        ax += w0 * bf2f(h0.x); ay += w0 * bf2f(h0.y);
        az += w0 * bf2f(h0.z); aw += w0 * bf2f(h0.w);
    }
    float4 r; r.x = ax; r.y = ay; r.z = az; r.w = aw;
    out4[(size_t)node * 64 + lane] = r;
}

// ---- K4-fallback: f32 aggregate (round-3 path) ----
__global__ __launch_bounds__(256) void agg_kernel(const float4* __restrict__ X4,
        const int* __restrict__ offs, const int* __restrict__ srcS,
        const float* __restrict__ wS, float4* __restrict__ agg4, int N) {
    int wave = threadIdx.x >> 6;
    int lane = threadIdx.x & 63;
    int node = blockIdx.x * 4 + wave;
    if (node >= N) return;
    int beg = offs[node], end = offs[node + 1];
    float ax = 0.f, ay = 0.f, az = 0.f, aw = 0.f;
    for (int e = beg; e < end; ++e) {
        int sN = srcS[e];
        float wt = wS[e];
        float4 xv = X4[(size_t)sN * 64 + lane];
        ax += wt * xv.x; ay += wt * xv.y; az += wt * xv.z; aw += wt * xv.w;
    }
    float4 r; r.x = ax; r.y = ay; r.z = az; r.w = aw;
    agg4[(size_t)node * 64 + lane] = r;
}

// ---- K5: out = A @ W^T via bf16 MFMA, IN-PLACE (A == out). BM=64, BN=256, BK=32. ----
__global__ __launch_bounds__(256) void gemm_kernel(const float* __restrict__ A,
        const float* __restrict__ Wp, float* __restrict__ out, int M) {
    __shared__ u16x8 Asm[4 * 64];    // [kc][row]  4KB
    __shared__ u16x8 Bsm[4 * 256];   // [kc][n]   16KB

    int tid  = threadIdx.x;
    int lane = tid & 63;
    int wn   = tid >> 6;
    int m0   = blockIdx.x * 64;

    f32x4 acc[4][4];
#pragma unroll
    for (int i = 0; i < 4; ++i)
#pragma unroll
        for (int j = 0; j < 4; ++j)
            acc[i][j] = (f32x4){0.f, 0.f, 0.f, 0.f};

    int arow = tid >> 2;
    int akc  = tid & 3;
    int grow = m0 + arow; if (grow > M - 1) grow = M - 1;
    const float* aBase = A + (size_t)grow * D + akc * 8;

    int l16 = lane & 15, lq = lane >> 4;

    for (int s = 0; s < 8; ++s) {
        int k0 = s * 32;
        {
            const float4* p = (const float4*)(aBase + k0);
            float4 v0 = p[0], v1 = p[1];
            u16x8 h;
            h[0] = f2bf(v0.x); h[1] = f2bf(v0.y); h[2] = f2bf(v0.z); h[3] = f2bf(v0.w);
            h[4] = f2bf(v1.x); h[5] = f2bf(v1.y); h[6] = f2bf(v1.z); h[7] = f2bf(v1.w);
            Asm[akc * 64 + arow] = h;
        }
#pragma unroll
        for (int j = 0; j < 4; ++j) {
            int n = j * 64 + (tid >> 2);
            const float4* p = (const float4*)(Wp + (size_t)n * D + k0 + akc * 8);
            float4 v0 = p[0], v1 = p[1];
            u16x8 h;
            h[0] = f2bf(v0.x); h[1] = f2bf(v0.y); h[2] = f2bf(v0.z); h[3] = f2bf(v0.w);
            h[4] = f2bf(v1.x); h[5] = f2bf(v1.y); h[6] = f2bf(v1.z); h[7] = f2bf(v1.w);
            Bsm[akc * 256 + n] = h;
        }
        __syncthreads();

        u16x8 af[4], bfr[4];
#pragma unroll
        for (int fm = 0; fm < 4; ++fm) af[fm] = Asm[lq * 64 + fm * 16 + l16];
#pragma unroll
        for (int fn = 0; fn < 4; ++fn) bfr[fn] = Bsm[lq * 256 + wn * 64 + fn * 16 + l16];
#pragma unroll
        for (int fm = 0; fm < 4; ++fm)
#pragma unroll
            for (int fn = 0; fn < 4; ++fn)
                acc[fm][fn] = __builtin_amdgcn_mfma_f32_16x16x32_bf16(
                    __builtin_bit_cast(bf16x8, af[fm]),
                    __builtin_bit_cast(bf16x8, bfr[fn]),
                    acc[fm][fn], 0, 0, 0);
        __syncthreads();
    }

#pragma unroll
    for (int fm = 0; fm < 4; ++fm)
#pragma unroll
        for (int fn = 0; fn < 4; ++fn)
#pragma unroll
            for (int r = 0; r < 4; ++r) {
                int row = m0 + fm * 16 + lq * 4 + r;
                int col = wn * 64 + fn * 16 + l16;
                if (row < M) out[(size_t)row * D + col] = acc[fm][fn][r];
            }
}

extern "C" void kernel_launch(void* const* d_in, const int* in_sizes, int n_in,
                              void* d_out, int out_size, void* d_ws, size_t ws_size,
                              hipStream_t stream) {
    const float* X  = (const float*)d_in[0];
    const int*   ei = (const int*)d_in[1];
    const float* ew = (const float*)d_in[2];
    const float* Wp = (const float*)d_in[3];
    float* out = (float*)d_out;

    int N = in_sizes[0] / D;       // 50000
    int E = in_sizes[2];           // 300000
    const int* dst = ei;
    const int* src = ei + E;
    int nb = (N + 1023) / 1024;    // 49

    size_t xbBytes  = (size_t)N * D * sizeof(unsigned short);        // 25.6 MB
    size_t csrInts  = (size_t)4 * N + 1 + nb + 2 * (size_t)E;        // ~0.8M ints
    size_t csrBytes = csrInts * sizeof(int);
    bool useBf16 = (ws_size >= xbBytes + csrBytes + 256);

    uint8_t* ws = (uint8_t*)d_ws;
    unsigned short* Xb = (unsigned short*)ws;
    int* csr = useBf16 ? (int*)(ws + ((xbBytes + 255) & ~(size_t)255)) : (int*)ws;

    int* cnt  = csr;                                   // N
    int* offs = cnt + N;                               // N+1
    int* cur  = offs + N + 1;                          // N
    int* srcS = cur + N;                               // E
    float* wS = (float*)(srcS + E);                    // E
    int* exsc = (int*)(wS + E);                        // N
    int* bsum = exsc + N;                              // nb

    hipMemsetAsync(cnt, 0, (size_t)N * sizeof(int), stream);
    if (useBf16) {
        size_t n8 = (size_t)N * D / 8;                 // 1.6M
        convert_kernel<<<dim3((unsigned)((n8 + 255) / 256)), dim3(256), 0, stream>>>(
            (const float4*)X, (u16x8*)Xb, n8);
    }
    count_kernel<<<dim3((E + 255) / 256), dim3(256), 0, stream>>>(dst, cnt, E);
    scan_local_kernel<<<dim3(nb), dim3(1024), 0, stream>>>(cnt, exsc, bsum, N);
    scan_bsum_kernel<<<dim3(1), dim3(1024), 0, stream>>>(bsum, nb);
    scan_finalize_kernel<<<dim3((N + 255) / 256), dim3(256), 0, stream>>>(exsc, bsum, offs, cur, N, E);
    fill_kernel<<<dim3((E + 255) / 256), dim3(256), 0, stream>>>(dst, src, ew, cur, srcS, wS, E);

    if (useBf16) {
        aggb_kernel<<<dim3((N + 3) / 4), dim3(256), 0, stream>>>((const ushort4*)Xb, offs, srcS, wS,
                                                                 (float4*)out, N);
    } else {
        agg_kernel<<<dim3((N + 3) / 4), dim3(256), 0, stream>>>((const float4*)X, offs, srcS, wS,
                                                                (float4*)out, N);
    }
    gemm_kernel<<<dim3((N + 63) / 64), dim3(256), 0, stream>>>(out, Wp, out, N);
}

// Round 5
// 183.929 us; speedup vs baseline: 1.7920x; 1.1421x over previous
//
#include <hip/hip_runtime.h>
#include <stdint.h>

#define D 256

typedef __bf16 bf16x8 __attribute__((ext_vector_type(8)));
typedef unsigned short u16x8 __attribute__((ext_vector_type(8)));
typedef float f32x4 __attribute__((ext_vector_type(4)));

static __device__ inline unsigned short f2bf(float f) {
    union { float f; unsigned u; } c; c.f = f;
    unsigned u = c.u + 0x7FFFu + ((c.u >> 16) & 1u);   // RNE round to bf16
    return (unsigned short)(u >> 16);
}
static __device__ inline float bf2f(unsigned short h) {
    union { unsigned u; float f; } c; c.u = (unsigned)h << 16;
    return c.f;
}

// ---- count: histogram of dst ----
__global__ void count_kernel(const int* __restrict__ dst, int* __restrict__ cnt, int E) {
    int e = blockIdx.x * blockDim.x + threadIdx.x;
    if (e < E) atomicAdd(&cnt[dst[e]], 1);
}

// ---- scan (3-phase hierarchical) ----
__global__ __launch_bounds__(1024) void scan_local_kernel(const int* __restrict__ cnt,
        int* __restrict__ exsc, int* __restrict__ bsum, int n) {
    int t = threadIdx.x;
    int idx = blockIdx.x * 1024 + t;
    int v = (idx < n) ? cnt[idx] : 0;
    __shared__ int tmp[1024];
    tmp[t] = v;
    __syncthreads();
    for (int off = 1; off < 1024; off <<= 1) {
        int u = 0;
        if (t >= off) u = tmp[t - off];
        __syncthreads();
        tmp[t] += u;
        __syncthreads();
    }
    if (idx < n) exsc[idx] = tmp[t] - v;
    if (t == 1023) bsum[blockIdx.x] = tmp[t];
}

__global__ __launch_bounds__(1024) void scan_bsum_kernel(int* __restrict__ bsum, int nb) {
    int t = threadIdx.x;
    int v = (t < nb) ? bsum[t] : 0;
    __shared__ int tmp[1024];
    tmp[t] = v;
    __syncthreads();
    for (int off = 1; off < 1024; off <<= 1) {
        int u = 0;
        if (t >= off) u = tmp[t - off];
        __syncthreads();
        tmp[t] += u;
        __syncthreads();
    }
    if (t < nb) bsum[t] = tmp[t] - v;
}

__global__ void scan_finalize_kernel(const int* __restrict__ exsc, const int* __restrict__ bsum,
        int* __restrict__ offs, int* __restrict__ cur, int n, int E) {
    int idx = blockIdx.x * blockDim.x + threadIdx.x;
    if (idx < n) {
        int o = exsc[idx] + bsum[idx >> 10];
        offs[idx] = o;
        cur[idx]  = o;
    }
    if (idx == 0) offs[n] = E;
}

// ---- standalone fill (fallback path) ----
__global__ void fill_kernel(const int* __restrict__ dst, const int* __restrict__ src,
        const float* __restrict__ ew, int* __restrict__ cur,
        int* __restrict__ srcS, float* __restrict__ wS, int E) {
    int e = blockIdx.x * blockDim.x + threadIdx.x;
    if (e < E) {
        int d = dst[e];
        int pos = atomicAdd(&cur[d], 1);
        srcS[pos] = src[e];
        wS[pos]   = ew[e];
    }
}

// ---- FAT kernel: blocks [0,gemmBlocks) compute xproj = bf16(X @ W^T);
//      blocks [gemmBlocks, ...) do the CSR bucket-fill (independent work). ----
__global__ __launch_bounds__(256) void gemm_fill_kernel(
        const float* __restrict__ X, const float* __restrict__ Wp,
        unsigned short* __restrict__ xproj, int M, int gemmBlocks,
        const int* __restrict__ dst, const int* __restrict__ src,
        const float* __restrict__ ew, int* __restrict__ cur,
        int* __restrict__ srcS, float* __restrict__ wS, int E) {
    __shared__ u16x8 Asm[4 * 64];    // [kc][row]  4KB
    __shared__ u16x8 Bsm[4 * 256];   // [kc][n]   16KB

    if ((int)blockIdx.x >= gemmBlocks) {
        int e = ((int)blockIdx.x - gemmBlocks) * 256 + threadIdx.x;
        if (e < E) {
            int d = dst[e];
            int pos = atomicAdd(&cur[d], 1);
            srcS[pos] = src[e];
            wS[pos]   = ew[e];
        }
        return;
    }

    int tid  = threadIdx.x;
    int lane = tid & 63;
    int wn   = tid >> 6;
    int m0   = blockIdx.x * 64;

    f32x4 acc[4][4];
#pragma unroll
    for (int i = 0; i < 4; ++i)
#pragma unroll
        for (int j = 0; j < 4; ++j)
            acc[i][j] = (f32x4){0.f, 0.f, 0.f, 0.f};

    int arow = tid >> 2;
    int akc  = tid & 3;
    int grow = m0 + arow; if (grow > M - 1) grow = M - 1;
    const float* aBase = X + (size_t)grow * D + akc * 8;

    int l16 = lane & 15, lq = lane >> 4;

    for (int s = 0; s < 8; ++s) {
        int k0 = s * 32;
        {
            const float4* p = (const float4*)(aBase + k0);
            float4 v0 = p[0], v1 = p[1];
            u16x8 h;
            h[0] = f2bf(v0.x); h[1] = f2bf(v0.y); h[2] = f2bf(v0.z); h[3] = f2bf(v0.w);
            h[4] = f2bf(v1.x); h[5] = f2bf(v1.y); h[6] = f2bf(v1.z); h[7] = f2bf(v1.w);
            Asm[akc * 64 + arow] = h;
        }
#pragma unroll
        for (int j = 0; j < 4; ++j) {
            int n = j * 64 + (tid >> 2);
            const float4* p = (const float4*)(Wp + (size_t)n * D + k0 + akc * 8);
            float4 v0 = p[0], v1 = p[1];
            u16x8 h;
            h[0] = f2bf(v0.x); h[1] = f2bf(v0.y); h[2] = f2bf(v0.z); h[3] = f2bf(v0.w);
            h[4] = f2bf(v1.x); h[5] = f2bf(v1.y); h[6] = f2bf(v1.z); h[7] = f2bf(v1.w);
            Bsm[akc * 256 + n] = h;
        }
        __syncthreads();

        u16x8 af[4], bfr[4];
#pragma unroll
        for (int fm = 0; fm < 4; ++fm) af[fm] = Asm[lq * 64 + fm * 16 + l16];
#pragma unroll
        for (int fn = 0; fn < 4; ++fn) bfr[fn] = Bsm[lq * 256 + wn * 64 + fn * 16 + l16];
#pragma unroll
        for (int fm = 0; fm < 4; ++fm)
#pragma unroll
            for (int fn = 0; fn < 4; ++fn)
                acc[fm][fn] = __builtin_amdgcn_mfma_f32_16x16x32_bf16(
                    __builtin_bit_cast(bf16x8, af[fm]),
                    __builtin_bit_cast(bf16x8, bfr[fn]),
                    acc[fm][fn], 0, 0, 0);
        __syncthreads();
    }

    // epilogue: write bf16 xproj. C/D map row=(lane>>4)*4+reg, col=lane&15
#pragma unroll
    for (int fm = 0; fm < 4; ++fm)
#pragma unroll
        for (int fn = 0; fn < 4; ++fn)
#pragma unroll
            for (int r = 0; r < 4; ++r) {
                int row = m0 + fm * 16 + lq * 4 + r;
                int col = wn * 64 + fn * 16 + l16;
                if (row < M) xproj[(size_t)row * D + col] = f2bf(acc[fm][fn][r]);
            }
}

// ---- agg from bf16 xproj rows (512B gather), f32 accumulate into d_out ----
__global__ __launch_bounds__(256) void aggp_kernel(const ushort4* __restrict__ P,
        const int* __restrict__ offs, const int* __restrict__ srcS,
        const float* __restrict__ wS, float4* __restrict__ out4, int N) {
    int wave = threadIdx.x >> 6;
    int lane = threadIdx.x & 63;
    int node = blockIdx.x * 4 + wave;
    if (node >= N) return;
    int beg = offs[node], end = offs[node + 1];
    float ax = 0.f, ay = 0.f, az = 0.f, aw = 0.f;
    int e = beg;
    for (; e + 3 < end; e += 4) {
        int s0 = srcS[e], s1 = srcS[e + 1], s2 = srcS[e + 2], s3 = srcS[e + 3];
        float w0 = wS[e], w1 = wS[e + 1], w2 = wS[e + 2], w3 = wS[e + 3];
        ushort4 h0 = P[(size_t)s0 * 64 + lane];
        ushort4 h1 = P[(size_t)s1 * 64 + lane];
        ushort4 h2 = P[(size_t)s2 * 64 + lane];
        ushort4 h3 = P[(size_t)s3 * 64 + lane];
        ax += w0 * bf2f(h0.x); ay += w0 * bf2f(h0.y); az += w0 * bf2f(h0.z); aw += w0 * bf2f(h0.w);
        ax += w1 * bf2f(h1.x); ay += w1 * bf2f(h1.y); az += w1 * bf2f(h1.z); aw += w1 * bf2f(h1.w);
        ax += w2 * bf2f(h2.x); ay += w2 * bf2f(h2.y); az += w2 * bf2f(h2.z); aw += w2 * bf2f(h2.w);
        ax += w3 * bf2f(h3.x); ay += w3 * bf2f(h3.y); az += w3 * bf2f(h3.z); aw += w3 * bf2f(h3.w);
    }
    for (; e < end; ++e) {
        int s0 = srcS[e];
        float w0 = wS[e];
        ushort4 h0 = P[(size_t)s0 * 64 + lane];
        ax += w0 * bf2f(h0.x); ay += w0 * bf2f(h0.y); az += w0 * bf2f(h0.z); aw += w0 * bf2f(h0.w);
    }
    float4 r; r.x = ax; r.y = ay; r.z = az; r.w = aw;
    out4[(size_t)node * 64 + lane] = r;
}

// ---- fallback path kernels (round-3 proven): f32 agg + in-place f32 GEMM ----
__global__ __launch_bounds__(256) void agg_kernel(const float4* __restrict__ X4,
        const int* __restrict__ offs, const int* __restrict__ srcS,
        const float* __restrict__ wS, float4* __restrict__ agg4, int N) {
    int wave = threadIdx.x >> 6;
    int lane = threadIdx.x & 63;
    int node = blockIdx.x * 4 + wave;
    if (node >= N) return;
    int beg = offs[node], end = offs[node + 1];
    float ax = 0.f, ay = 0.f, az = 0.f, aw = 0.f;
    for (int e = beg; e < end; ++e) {
        int sN = srcS[e];
        float wt = wS[e];
        float4 xv = X4[(size_t)sN * 64 + lane];
        ax += wt * xv.x; ay += wt * xv.y; az += wt * xv.z; aw += wt * xv.w;
    }
    float4 r; r.x = ax; r.y = ay; r.z = az; r.w = aw;
    agg4[(size_t)node * 64 + lane] = r;
}

__global__ __launch_bounds__(256) void gemm_kernel(const float* __restrict__ A,
        const float* __restrict__ Wp, float* __restrict__ out, int M) {
    __shared__ u16x8 Asm[4 * 64];
    __shared__ u16x8 Bsm[4 * 256];
    int tid  = threadIdx.x;
    int lane = tid & 63;
    int wn   = tid >> 6;
    int m0   = blockIdx.x * 64;
    f32x4 acc[4][4];
#pragma unroll
    for (int i = 0; i < 4; ++i)
#pragma unroll
        for (int j = 0; j < 4; ++j)
            acc[i][j] = (f32x4){0.f, 0.f, 0.f, 0.f};
    int arow = tid >> 2;
    int akc  = tid & 3;
    int grow = m0 + arow; if (grow > M - 1) grow = M - 1;
    const float* aBase = A + (size_t)grow * D + akc * 8;
    int l16 = lane & 15, lq = lane >> 4;
    for (int s = 0; s < 8; ++s) {
        int k0 = s * 32;
        {
            const float4* p = (const float4*)(aBase + k0);
            float4 v0 = p[0], v1 = p[1];
            u16x8 h;
            h[0] = f2bf(v0.x); h[1] = f2bf(v0.y); h[2] = f2bf(v0.z); h[3] = f2bf(v0.w);
            h[4] = f2bf(v1.x); h[5] = f2bf(v1.y); h[6] = f2bf(v1.z); h[7] = f2bf(v1.w);
            Asm[akc * 64 + arow] = h;
        }
#pragma unroll
        for (int j = 0; j < 4; ++j) {
            int n = j * 64 + (tid >> 2);
            const float4* p = (const float4*)(Wp + (size_t)n * D + k0 + akc * 8);
            float4 v0 = p[0], v1 = p[1];
            u16x8 h;
            h[0] = f2bf(v0.x); h[1] = f2bf(v0.y); h[2] = f2bf(v0.z); h[3] = f2bf(v0.w);
            h[4] = f2bf(v1.x); h[5] = f2bf(v1.y); h[6] = f2bf(v1.z); h[7] = f2bf(v1.w);
            Bsm[akc * 256 + n] = h;
        }
        __syncthreads();
        u16x8 af[4], bfr[4];
#pragma unroll
        for (int fm = 0; fm < 4; ++fm) af[fm] = Asm[lq * 64 + fm * 16 + l16];
#pragma unroll
        for (int fn = 0; fn < 4; ++fn) bfr[fn] = Bsm[lq * 256 + wn * 64 + fn * 16 + l16];
#pragma unroll
        for (int fm = 0; fm < 4; ++fm)
#pragma unroll
            for (int fn = 0; fn < 4; ++fn)
                acc[fm][fn] = __builtin_amdgcn_mfma_f32_16x16x32_bf16(
                    __builtin_bit_cast(bf16x8, af[fm]),
                    __builtin_bit_cast(bf16x8, bfr[fn]),
                    acc[fm][fn], 0, 0, 0);
        __syncthreads();
    }
#pragma unroll
    for (int fm = 0; fm < 4; ++fm)
#pragma unroll
        for (int fn = 0; fn < 4; ++fn)
#pragma unroll
            for (int r = 0; r < 4; ++r) {
                int row = m0 + fm * 16 + lq * 4 + r;
                int col = wn * 64 + fn * 16 + l16;
                if (row < M) out[(size_t)row * D + col] = acc[fm][fn][r];
            }
}

extern "C" void kernel_launch(void* const* d_in, const int* in_sizes, int n_in,
                              void* d_out, int out_size, void* d_ws, size_t ws_size,
                              hipStream_t stream) {
    const float* X  = (const float*)d_in[0];
    const int*   ei = (const int*)d_in[1];
    const float* ew = (const float*)d_in[2];
    const float* Wp = (const float*)d_in[3];
    float* out = (float*)d_out;

    int N = in_sizes[0] / D;       // 50000
    int E = in_sizes[2];           // 300000
    const int* dst = ei;
    const int* src = ei + E;
    int nb = (N + 1023) / 1024;    // 49

    size_t xpBytes  = (size_t)N * D * sizeof(unsigned short);        // 25.6 MB
    size_t csrInts  = (size_t)4 * N + 1 + nb + 2 * (size_t)E;
    size_t csrBytes = csrInts * sizeof(int);
    bool planB = (ws_size >= xpBytes + csrBytes + 256);

    uint8_t* ws = (uint8_t*)d_ws;
    unsigned short* xproj = (unsigned short*)ws;
    int* csr = planB ? (int*)(ws + ((xpBytes + 255) & ~(size_t)255)) : (int*)ws;

    int* cnt  = csr;                                   // N
    int* offs = cnt + N;                               // N+1
    int* cur  = offs + N + 1;                          // N
    int* srcS = cur + N;                               // E
    float* wS = (float*)(srcS + E);                    // E
    int* exsc = (int*)(wS + E);                        // N
    int* bsum = exsc + N;                              // nb

    hipMemsetAsync(cnt, 0, (size_t)N * sizeof(int), stream);
    count_kernel<<<dim3((E + 255) / 256), dim3(256), 0, stream>>>(dst, cnt, E);
    scan_local_kernel<<<dim3(nb), dim3(1024), 0, stream>>>(cnt, exsc, bsum, N);
    scan_bsum_kernel<<<dim3(1), dim3(1024), 0, stream>>>(bsum, nb);
    scan_finalize_kernel<<<dim3((N + 255) / 256), dim3(256), 0, stream>>>(exsc, bsum, offs, cur, N, E);

    if (planB) {
        int gemmBlocks = (N + 63) / 64;        // 782
        int fillBlocks = (E + 255) / 256;      // 1172
        gemm_fill_kernel<<<dim3(gemmBlocks + fillBlocks), dim3(256), 0, stream>>>(
            X, Wp, xproj, N, gemmBlocks, dst, src, ew, cur, srcS, wS, E);
        aggp_kernel<<<dim3((N + 3) / 4), dim3(256), 0, stream>>>(
            (const ushort4*)xproj, offs, srcS, wS, (float4*)out, N);
    } else {
        fill_kernel<<<dim3((E + 255) / 256), dim3(256), 0, stream>>>(dst, src, ew, cur, srcS, wS, E);
        agg_kernel<<<dim3((N + 3) / 4), dim3(256), 0, stream>>>((const float4*)X, offs, srcS, wS,
                                                                (float4*)out, N);
        gemm_kernel<<<dim3((N + 63) / 64), dim3(256), 0, stream>>>(out, Wp, out, N);
    }
}